// Round 14
// baseline (641.631 us; speedup 1.0000x reference)
//
#include <hip/hip_runtime.h>
#include <hip/hip_bf16.h>

typedef __attribute__((ext_vector_type(8))) short s16x8;
typedef __attribute__((ext_vector_type(4))) float f32x4;

#define MFMA_B16(a, b, c) __builtin_amdgcn_mfma_f32_16x16x32_bf16((a), (b), (c), 0, 0, 0)

static __device__ __forceinline__ short f2bf(float f) {
    __hip_bfloat16 h = __float2bfloat16(f);
    return __builtin_bit_cast(short, h);
}
static __device__ __forceinline__ float rcp_f(float x) {
    return __builtin_amdgcn_rcpf(x);
}

// pre-pass: X fp32 -> bf16 in workspace
__global__ void xcvt_kernel(const float* __restrict__ X, short* __restrict__ Xb, int n) {
    int i = (blockIdx.x * 256 + threadIdx.x) * 4;
    if (i < n) {
        float4 v = *(const float4*)(X + i);
        short4 o;
        o.x = f2bf(v.x); o.y = f2bf(v.y); o.z = f2bf(v.z); o.w = f2bf(v.w);
        *(short4*)(Xb + i) = o;
    }
}

// Ensemble LSTM. R23 = deeper register diet for co-residency. WG = (series, batch
// pair), 512 WGs, target 2 WGs/CU. R22 evidence: trace VGPR_Count is ARCH-ONLY
// (R17's 64 extra transient regs didn't move it; R22's -32 regs of data moved it
// only -4) -> occupancy needs arch + acc(AGPR, invisible) <= 128. R22: ~104+~40 >
// 128 -> 1 WG. R23 cuts: Bx (16 regs, read 1x per 4 steps) -> per-thread LDS slab
// (32KB); BV compressed 32KB -> 8KB per-(w,col) broadcast slab. Arch ~88 + acc
// ~36-40 ~ 124-128. LDS 56KB/WG (static-legal), 112KB/CU for 2 WGs. Mechanism if
// co-resident: two independent-barrier WGs interleave ~56% idle serial chains;
// MFMA issue 2x617=1234cy fits the 1488cy step.
// PRE-COMMITTED: occupancy ~23 again -> register wall is structural; revert to R21
// (342us best) and declare ceiling.
// Journal:
//   R5/R6 pack +15 | R7 asm barrier +21 | R8 LDS atomic +834 | R10 pingpong 0
//   R11 masked LDS +105 | R12 bounds(,4) spill | R13 grid512 2x | R14 compact h +11
//   R15 fused xcvt 0 | R16 grouped xproj -6 | R17 depth-1 chains +33
//   R18 dyn reg idx +873 | R19 symmetric pred +7 | R21 VALU cuts -13 (342.5 best)
//   R22 shallow diet (Bp,biasv->LDS) -> no co-residency (arch 104 + invisible acc)
template<bool BF16X>
__global__ __launch_bounds__(512, 2)
void clstm_kernel(const float* __restrict__ X,
                  const short* __restrict__ Xb,
                  const float* __restrict__ W_ih,
                  const float* __restrict__ W_hh,
                  const float* __restrict__ b_ih,
                  const float* __restrict__ b_hh,
                  const float* __restrict__ W_out,
                  const float* __restrict__ b_out,
                  float* __restrict__ out)
{
    constexpr int B = 32, T = 512, N = 32, H = 128, G = 512;  // G = 4H
    constexpr int HT_OFF = B * T * N;
    constexpr int CT_OFF = HT_OFF + N * B * H;
    constexpr int PRED_OFF = 8192;    // 4KB: 2 batches x T floats
    constexpr int BP_OFF   = 12288;   // 4KB: pred B frags, kt*1024 + L*16
    constexpr int BV_OFF   = 16384;   // 8KB: bias splats per (tt, w, col)
    constexpr int BX_OFF   = 24576;   // 32KB: Bx frags per (tt, tid)
    constexpr float C1  = 1.4426950408889634f;    // log2(e)
    constexpr float C2  = 2.8853900817779268f;    // 2*log2(e)
    constexpr float CFX = -0.34657359027997264f;  // -1/(2*log2(e))

    __shared__ __align__(16) unsigned char smem[57344];

    const int tid  = threadIdx.x;
    const int w    = tid >> 6;   // wave 0..7
    const int L    = tid & 63;
    const int col  = L & 15;
    const int quad = L >> 4;
    const int n    = blockIdx.x & 31;   // series
    const int bgrp = blockIdx.x >> 5;   // batch pair 0..15

    // ---- loop-invariant weight fragments (fp32 -> bf16, once), PRESCALED ----
    s16x8 Bh[4][4];  // [gate tt][kt] scaled by s_tt (regs: 64 VGPR; Bx/bias -> LDS)
#pragma unroll
    for (int tt = 0; tt < 4; ++tt) {
        const float s_tt = (tt == 2) ? -C2 : -C1;
        const int g = (w + 8 * tt) * 16 + col;
        const float* whr = W_hh + ((size_t)n * G + g) * H + quad * 8;
#pragma unroll
        for (int kt = 0; kt < 4; ++kt) {
            const float* p = whr + kt * 32;
#pragma unroll
            for (int jj = 0; jj < 8; ++jj) Bh[tt][kt][jj] = f2bf(s_tt * p[jj]);
        }
        // Bx -> LDS slab (per-thread 16B)
        {
            const float* wir = W_ih + ((size_t)n * G + g) * N + quad * 8;
            s16x8 bx;
#pragma unroll
            for (int jj = 0; jj < 8; ++jj) bx[jj] = f2bf(s_tt * wir[jj]);
            *(s16x8*)(smem + BX_OFF + tt * 8192 + tid * 16) = bx;
        }
        // bias splat -> compressed LDS slab (per (w,col); quad 0 writes)
        if (quad == 0) {
            const float bb = s_tt * (b_ih[n * G + g] + b_hh[n * G + g]);
            *(f32x4*)(smem + BV_OFF + tt * 2048 + ((w << 4) | col) * 16) =
                (f32x4){bb, bb, bb, bb};
        }
    }

    // zero pred-B slab region + h frag dbuf BEFORE first barrier
    if (tid < 256) *(float4*)(smem + BP_OFF + tid * 16) = make_float4(0.f, 0.f, 0.f, 0.f);
    const float bo = b_out[n];
    *(float4*)(smem + tid * 16) = make_float4(0.f, 0.f, 0.f, 0.f);
    __syncthreads();
    if (col == 0) {
#pragma unroll
        for (int kt = 0; kt < 4; ++kt) {
            s16x8 f;
            const float* wp = W_out + n * H + kt * 32 + quad * 8;
#pragma unroll
            for (int jj = 0; jj < 8; ++jj) f[jj] = f2bf(wp[jj]);
            *(s16x8*)(smem + BP_OFF + kt * 1024 + L * 16) = f;
        }
    }

    // ---- h writer offset: rows 4*quad..+3 (replicated), j = w*16+col ----
    int wboff;
    {
        const int j = w * 16 + col;
        wboff = (j >> 5) * 1024 + (((((j >> 3) & 3) << 4) | (quad << 2)) * 16) + (j & 7) * 2;
    }
    const bool cellactive = (quad < 2);   // 2 real batches

    // ---- grouped x loader: A row = 4*batch + tsub; batches 0..1, col>=8 duplicates ----
    const int xb = bgrp * 2 + ((col >> 2) & 1);
    const int ts = col & 3;
    const float* xp  = X + ((size_t)xb * T + ts) * N + quad * 8;
    const short* xbp = BF16X ? (Xb + ((size_t)xb * T + ts) * N + quad * 8) : nullptr;

    auto loadxg = [&](int tg) -> s16x8 {
        if constexpr (BF16X) {
            return *(const s16x8*)(xbp + (size_t)tg * N);
        } else {
            float4 lo = *(const float4*)(xp + (size_t)tg * N);
            float4 hi = *(const float4*)(xp + (size_t)tg * N + 4);
            s16x8 r;
            r[0] = f2bf(lo.x); r[1] = f2bf(lo.y); r[2] = f2bf(lo.z); r[3] = f2bf(lo.w);
            r[4] = f2bf(hi.x); r[5] = f2bf(hi.y); r[6] = f2bf(hi.z); r[7] = f2bf(hi.w);
            return r;
        }
    };

    float cstp = 0.f, hlast = 0.f;   // cstp = -2C1 * c (scaled state)

    // prologue: x for group 0 and prefetch for group 1
    s16x8 xgC = loadxg(0);
    s16x8 xgN = loadxg(4);

    __syncthreads();   // covers h-zero, BX/BV/BP slabs

#define STEP(P, TCUR, J)                                                            \
    {                                                                               \
        const unsigned char* rb = smem + (P) * 4096;                                \
        s16x8 Af[4];                                                                \
        _Pragma("unroll")                                                           \
        for (int kt = 0; kt < 4; ++kt)                                              \
            Af[kt] = *(const s16x8*)(rb + kt * 1024 + L * 16);                      \
        f32x4 cur[4];                                                               \
        _Pragma("unroll")                                                           \
        for (int tt = 0; tt < 4; ++tt)                                              \
            cur[tt] = MFMA_B16(Af[0], Bh[tt][0], acc4[tt]);                         \
        _Pragma("unroll")                                                           \
        for (int kt = 1; kt < 4; ++kt) {                                            \
            _Pragma("unroll")                                                       \
            for (int tt = 0; tt < 4; ++tt)                                          \
                cur[tt] = MFMA_B16(Af[kt], Bh[tt][kt], cur[tt]);                    \
        }                                                                           \
        if (w == ((TCUR) & 7)) {                                                    \
            f32x4 pacc = (f32x4){0.f, 0.f, 0.f, 0.f};                               \
            _Pragma("unroll")                                                       \
            for (int kt = 0; kt < 4; ++kt) {                                        \
                s16x8 Bpk = *(const s16x8*)(smem + BP_OFF + kt * 1024 + L * 16);    \
                pacc = MFMA_B16(Af[kt], Bpk, pacc);                                 \
            }                                                                       \
            if ((TCUR) > 0 && col == 0 && cellactive)                               \
                *(float*)(smem + PRED_OFF + ((quad << 9) + (TCUR) - 1) * 4) =       \
                    pacc[0] + bo;                                                   \
        }                                                                           \
        /* epilogue: gates pre-scaled -> direct exp2; scaled c-state */             \
        {                                                                           \
            const float iv = cur[0][(J)], fv = cur[1][(J)];                         \
            const float gv = cur[2][(J)], ov = cur[3][(J)];                         \
            const float ei = exp2f(iv);                                             \
            const float ef = exp2f(fv);                                             \
            const float eg = exp2f(gv);                                             \
            const float eo = exp2f(ov);                                             \
            const float sf  = rcp_f(1.0f + ef);                                     \
            const float tgm = __builtin_fmaf(C2, eg, -C2);                          \
            const float itgp = tgm * rcp_f((1.0f + ei) * (1.0f + eg));              \
            const float ccp = __builtin_fmaf(sf, cstp, itgp);                       \
            cstp = ccp;                                                             \
            const float ec = exp2f(ccp);                                            \
            const float hv = (1.0f - ec) * rcp_f((1.0f + eo) * (1.0f + ec));        \
            hlast = hv;                                                             \
            const short hb = f2bf(hv);                                              \
            unsigned char* wbp = smem + ((P) ^ 1) * 4096 + wboff;                   \
            *(short*)(wbp)      = hb;                                               \
            *(short*)(wbp + 16) = hb;                                               \
            *(short*)(wbp + 32) = hb;                                               \
            *(short*)(wbp + 48) = hb;                                               \
        }                                                                           \
        __syncthreads();                                                            \
    }

#pragma unroll 1
    for (int tg = 0; tg < T; tg += 4) {
        // group top: scaled xproj(+bias) for steps tg..tg+3; Bx + bias from LDS.
        f32x4 acc4[4];
#pragma unroll
        for (int tt = 0; tt < 4; ++tt) {
            const s16x8 bx = *(const s16x8*)(smem + BX_OFF + tt * 8192 + tid * 16);
            const f32x4 bv = *(const f32x4*)(smem + BV_OFF + tt * 2048 + ((w << 4) | col) * 16);
            acc4[tt] = MFMA_B16(xgC, bx, bv);
        }
        xgC = xgN;
        xgN = loadxg((tg + 8 < T) ? (tg + 8) : (T - 4));
        STEP(0, tg + 0, 0)
        STEP(1, tg + 1, 1)
        STEP(0, tg + 2, 2)
        STEP(1, tg + 3, 3)
    }
#undef STEP

    // ---- tail pred: t = T-1 uses h_{T-1}, sitting in buffer 0 ----
    if (w == 0) {
        f32x4 pacc = (f32x4){0.f, 0.f, 0.f, 0.f};
#pragma unroll
        for (int kt = 0; kt < 4; ++kt) {
            s16x8 Af = *(const s16x8*)(smem + kt * 1024 + L * 16);
            s16x8 Bpk = *(const s16x8*)(smem + BP_OFF + kt * 1024 + L * 16);
            pacc = MFMA_B16(Af, Bpk, pacc);
        }
        if (col == 0 && cellactive)
            *(float*)(smem + PRED_OFF + ((quad << 9) + (T - 1)) * 4) = pacc[0] + bo;
    }
    __syncthreads();

    // ---- flush pred stage -> global: 2 batches x T ----
#pragma unroll
    for (int e = tid; e < 2 * T; e += 512) {
        const int b = e >> 9, t = e & (T - 1);
        out[((size_t)(bgrp * 2 + b) * T + t) * N + n] =
            *(const float*)(smem + PRED_OFF + e * 4);
    }

    // ---- final hT, cT (unscale c) ----
    if (cellactive) {
        const int bglob = bgrp * 2 + quad;
        const int j = w * 16 + col;
        out[HT_OFF + ((size_t)n * B + bglob) * H + j] = hlast;
        out[CT_OFF + ((size_t)n * B + bglob) * H + j] = cstp * CFX;
    }
}

extern "C" void kernel_launch(void* const* d_in, const int* in_sizes, int n_in,
                              void* d_out, int out_size, void* d_ws, size_t ws_size,
                              hipStream_t stream) {
    const float* X     = (const float*)d_in[0];
    const float* W_ih  = (const float*)d_in[1];
    const float* W_hh  = (const float*)d_in[2];
    const float* b_ih  = (const float*)d_in[3];
    const float* b_hh  = (const float*)d_in[4];
    const float* W_out = (const float*)d_in[5];
    const float* b_out = (const float*)d_in[6];
    float* out = (float*)d_out;

    const int xelems = 32 * 512 * 32;  // B*T*N
    const bool usebf = ws_size >= (size_t)xelems * sizeof(short);

    if (usebf) {
        short* Xb = (short*)d_ws;
        xcvt_kernel<<<dim3(xelems / 1024), dim3(256), 0, stream>>>(X, Xb, xelems);
        clstm_kernel<true><<<dim3(512), dim3(512), 0, stream>>>(
            X, Xb, W_ih, W_hh, b_ih, b_hh, W_out, b_out, out);
    } else {
        clstm_kernel<false><<<dim3(512), dim3(512), 0, stream>>>(
            X, nullptr, W_ih, W_hh, b_ih, b_hh, W_out, b_out, out);
    }
}

// Round 15
// 340.505 us; speedup vs baseline: 1.8843x; 1.8843x over previous
//
#include <hip/hip_runtime.h>
#include <hip/hip_bf16.h>

typedef __attribute__((ext_vector_type(8))) short s16x8;
typedef __attribute__((ext_vector_type(4))) float f32x4;

#define MFMA_B16(a, b, c) __builtin_amdgcn_mfma_f32_16x16x32_bf16((a), (b), (c), 0, 0, 0)

static __device__ __forceinline__ short f2bf(float f) {
    __hip_bfloat16 h = __float2bfloat16(f);
    return __builtin_bit_cast(short, h);
}
static __device__ __forceinline__ float rcp_f(float x) {
    return __builtin_amdgcn_rcpf(x);
}

// pre-pass: X fp32 -> bf16 in workspace
__global__ void xcvt_kernel(const float* __restrict__ X, short* __restrict__ Xb, int n) {
    int i = (blockIdx.x * 256 + threadIdx.x) * 4;
    if (i < n) {
        float4 v = *(const float4*)(X + i);
        short4 o;
        o.x = f2bf(v.x); o.y = f2bf(v.y); o.z = f2bf(v.z); o.w = f2bf(v.w);
        *(short4*)(Xb + i) = o;
    }
}

// Ensemble LSTM, batch-split-8: WG = (series n, 4 batches). 256 WGs = 256 CUs.
// R24 = exact revert to R21 (342.5us best), closing the co-residency line.
// R22/R23 verdict: arch VGPR diet (104->76) never moved occupancy (23%) because the
// unified-file AGPR side (Bh 64 + acc working set, invisible to the trace) keeps the
// per-wave total >128. Resident-weight design => max 3 waves/SIMD => 1 WG/CU,
// structurally. Moving weights to LDS to fit would re-create the R11-class LDS-read
// regression (32KB/step/WG on the critical path). Wave-private no-barrier
// decomposition needs ~512 B-frag regs/wave: impossible.
// Step budget at R21: 1491cy = ~650 MFMA issue + ~840 barrier-locked serial chain
// (lgkm -> 4-deep gate chain -> 5-transcendental epilogue -> replicated h write ->
// barrier drain). VALUBusy-MfmaUtil squeezed to 2.8pts. Eliminated as critical path:
// MFMA issue (R16), LDS traffic/conflicts (R11/R14/R19), schedule order (R10),
// C-chain depth (R17), occupancy (R12/R13/R22/R23), launches (R15), straggler (R19),
// VALU movs (R21). T=512 sequential steps of a nonlinear recurrence = the floor.
// Journal:
//   R5/R6 pack +15 | R7 asm barrier +21 | R8 LDS atomic +834 | R10 pingpong 0
//   R11 masked LDS +105 | R12 bounds(,4) spill | R13 grid512 2x | R14 compact h +11
//   R15 fused xcvt 0 | R16 grouped xproj -6 | R17 depth-1 chains +33
//   R18 dyn reg idx +873 | R19 symmetric pred +7 | R21 VALU cuts -13 (342.5 BEST)
//   R22 shallow diet -> no co-res | R23 deep diet (arch 76!) -> no co-res (AGPRs)
template<bool BF16X>
__global__ __launch_bounds__(512, 2)
void clstm_kernel(const float* __restrict__ X,
                  const short* __restrict__ Xb,
                  const float* __restrict__ W_ih,
                  const float* __restrict__ W_hh,
                  const float* __restrict__ b_ih,
                  const float* __restrict__ b_hh,
                  const float* __restrict__ W_out,
                  const float* __restrict__ b_out,
                  float* __restrict__ out)
{
    constexpr int B = 32, T = 512, N = 32, H = 128, G = 512;  // G = 4H
    constexpr int HT_OFF = B * T * N;
    constexpr int CT_OFF = HT_OFF + N * B * H;
    constexpr int PRED_OFF = 8192;
    constexpr float C1  = 1.4426950408889634f;    // log2(e)
    constexpr float C2  = 2.8853900817779268f;    // 2*log2(e)
    constexpr float CFX = -0.34657359027997264f;  // -1/(2*log2(e)) : cc = cc'*CFX

    __shared__ __align__(16) unsigned char smem[16384];

    const int tid  = threadIdx.x;
    const int w    = tid >> 6;   // wave 0..7
    const int L    = tid & 63;
    const int col  = L & 15;
    const int quad = L >> 4;
    const int n    = blockIdx.x & 31;   // series
    const int bgrp = blockIdx.x >> 5;   // batch group (4 batches)

    // ---- loop-invariant weight fragments (fp32 -> bf16, once), PRESCALED ----
    s16x8 Bh[4][4];  // [gate tt][kt]   scaled by s_tt
    s16x8 Bx[4];     // [gate tt]       scaled by s_tt
    f32x4 biasv[4];  // bias broadcast, scaled by s_tt
#pragma unroll
    for (int tt = 0; tt < 4; ++tt) {
        const float s_tt = (tt == 2) ? -C2 : -C1;
        const int g = (w + 8 * tt) * 16 + col;
        const float* whr = W_hh + ((size_t)n * G + g) * H + quad * 8;
#pragma unroll
        for (int kt = 0; kt < 4; ++kt) {
            const float* p = whr + kt * 32;
#pragma unroll
            for (int jj = 0; jj < 8; ++jj) Bh[tt][kt][jj] = f2bf(s_tt * p[jj]);
        }
        const float* wir = W_ih + ((size_t)n * G + g) * N + quad * 8;
#pragma unroll
        for (int jj = 0; jj < 8; ++jj) Bx[tt][jj] = f2bf(s_tt * wir[jj]);
        const float bb = s_tt * (b_ih[n * G + g] + b_hh[n * G + g]);
        biasv[tt] = (f32x4){bb, bb, bb, bb};
    }

    // ---- pred tile: B col 0 = W_out, rotated across waves (UNSCALED path) ----
    s16x8 Bp[4];
    const float bo = b_out[n];
    const f32x4 bov = (f32x4){bo, bo, bo, bo};
#pragma unroll
    for (int kt = 0; kt < 4; ++kt) {
        const float* wp = W_out + n * H + kt * 32 + quad * 8;
#pragma unroll
        for (int jj = 0; jj < 8; ++jj)
            Bp[kt][jj] = (col == 0) ? f2bf(wp[jj]) : (short)0;
    }

    // ---- h writer offset: base row m=4*quad at (j-frag layout); +16/+32/+48 replicas ----
    int wboff;
    {
        const int j = w * 16 + col;
        wboff = (j >> 5) * 1024 + (((((j >> 3) & 3) << 4) | (quad << 2)) * 16) + (j & 7) * 2;
    }

    // ---- grouped x loader: ALL lanes; A row = 4*batch + tsub ----
    const int xb = bgrp * 4 + (col >> 2);
    const int ts = col & 3;
    const float* xp  = X + ((size_t)xb * T + ts) * N + quad * 8;
    const short* xbp = BF16X ? (Xb + ((size_t)xb * T + ts) * N + quad * 8) : nullptr;

    auto loadxg = [&](int tg) -> s16x8 {
        if constexpr (BF16X) {
            return *(const s16x8*)(xbp + (size_t)tg * N);
        } else {
            float4 lo = *(const float4*)(xp + (size_t)tg * N);
            float4 hi = *(const float4*)(xp + (size_t)tg * N + 4);
            s16x8 r;
            r[0] = f2bf(lo.x); r[1] = f2bf(lo.y); r[2] = f2bf(lo.z); r[3] = f2bf(lo.w);
            r[4] = f2bf(hi.x); r[5] = f2bf(hi.y); r[6] = f2bf(hi.z); r[7] = f2bf(hi.w);
            return r;
        }
    };

    // zero frag buffers (h_{-1}=0 for all rows) + pred stage
    *(float4*)(smem + tid * 16)        = make_float4(0.f, 0.f, 0.f, 0.f);
    *(float4*)(smem + 8192 + tid * 16) = make_float4(0.f, 0.f, 0.f, 0.f);

    float cstp = 0.f, hlast = 0.f;   // cstp = -2C1 * c  (scaled state)

    // prologue: x for group 0 and prefetch for group 1
    s16x8 xgC = loadxg(0);
    s16x8 xgN = loadxg(4);

    __syncthreads();

// Per step: Af from LDS; gate MFMA chain with C = acc4[tt] DIRECT (rows 4q+J hold
// real h via replication, so element [J] = gates for step tg+J). Epilogue reads
// cur[tt][J]; h replicated to 4 rows for the next step.
#define STEP(P, TCUR, J)                                                            \
    {                                                                               \
        const unsigned char* rb = smem + (P) * 4096;                                \
        s16x8 Af[4];                                                                \
        _Pragma("unroll")                                                           \
        for (int kt = 0; kt < 4; ++kt)                                              \
            Af[kt] = *(const s16x8*)(rb + kt * 1024 + L * 16);                      \
        f32x4 cur[4];                                                               \
        _Pragma("unroll")                                                           \
        for (int tt = 0; tt < 4; ++tt)                                              \
            cur[tt] = MFMA_B16(Af[0], Bh[tt][0], acc4[tt]);                         \
        _Pragma("unroll")                                                           \
        for (int kt = 1; kt < 4; ++kt) {                                            \
            _Pragma("unroll")                                                       \
            for (int tt = 0; tt < 4; ++tt)                                          \
                cur[tt] = MFMA_B16(Af[kt], Bh[tt][kt], cur[tt]);                    \
        }                                                                           \
        if (w == ((TCUR) & 7)) {                                                    \
            f32x4 pacc = bov;                                                       \
            _Pragma("unroll")                                                       \
            for (int kt = 0; kt < 4; ++kt)                                          \
                pacc = MFMA_B16(Af[kt], Bp[kt], pacc);                              \
            if ((TCUR) > 0 && col == 0)                                             \
                *(float*)(smem + PRED_OFF + ((quad << 9) + (TCUR) - 1) * 4) =       \
                    pacc[0];                                                        \
        }                                                                           \
        /* epilogue: gates pre-scaled -> direct exp2; scaled c-state */             \
        {                                                                           \
            const float iv = cur[0][(J)], fv = cur[1][(J)];                         \
            const float gv = cur[2][(J)], ov = cur[3][(J)];                         \
            const float ei = exp2f(iv);                                             \
            const float ef = exp2f(fv);                                             \
            const float eg = exp2f(gv);                                             \
            const float eo = exp2f(ov);                                             \
            const float sf  = rcp_f(1.0f + ef);                                     \
            const float tgm = __builtin_fmaf(C2, eg, -C2);                          \
            const float itgp = tgm * rcp_f((1.0f + ei) * (1.0f + eg));              \
            const float ccp = __builtin_fmaf(sf, cstp, itgp);                       \
            cstp = ccp;                                                             \
            const float ec = exp2f(ccp);                                            \
            const float hv = (1.0f - ec) * rcp_f((1.0f + eo) * (1.0f + ec));        \
            hlast = hv;                                                             \
            const short hb = f2bf(hv);                                              \
            unsigned char* wbp = smem + ((P) ^ 1) * 4096 + wboff;                   \
            *(short*)(wbp)      = hb;                                               \
            *(short*)(wbp + 16) = hb;                                               \
            *(short*)(wbp + 32) = hb;                                               \
            *(short*)(wbp + 48) = hb;                                               \
        }                                                                           \
        __syncthreads();                                                            \
    }

#pragma unroll 1
    for (int tg = 0; tg < T; tg += 4) {
        // group top: 4 MFMAs produce scaled xproj(+bias) for steps tg..tg+3;
        // prefetch next group's x.
        f32x4 acc4[4];
#pragma unroll
        for (int tt = 0; tt < 4; ++tt)
            acc4[tt] = MFMA_B16(xgC, Bx[tt], biasv[tt]);
        xgC = xgN;
        xgN = loadxg((tg + 8 < T) ? (tg + 8) : (T - 4));
        STEP(0, tg + 0, 0)
        STEP(1, tg + 1, 1)
        STEP(0, tg + 2, 2)
        STEP(1, tg + 3, 3)
    }
#undef STEP

    // ---- tail pred: t = T-1 uses h_{T-1}, sitting in buffer 0 ----
    if (w == 0) {
        f32x4 pacc = bov;
#pragma unroll
        for (int kt = 0; kt < 4; ++kt) {
            s16x8 Af = *(const s16x8*)(smem + kt * 1024 + L * 16);
            pacc = MFMA_B16(Af, Bp[kt], pacc);
        }
        if (col == 0)
            *(float*)(smem + PRED_OFF + ((quad << 9) + (T - 1)) * 4) = pacc[0];
    }
    __syncthreads();

    // ---- flush pred stage -> global ----
#pragma unroll
    for (int e = tid; e < 4 * T; e += 512) {
        const int b = e >> 9, t = e & (T - 1);
        out[((size_t)(bgrp * 4 + b) * T + t) * N + n] =
            *(const float*)(smem + PRED_OFF + e * 4);
    }

    // ---- final hT, cT (unscale c) ----
    {
        const int bglob = bgrp * 4 + quad;
        const int j = w * 16 + col;
        out[HT_OFF + ((size_t)n * B + bglob) * H + j] = hlast;
        out[CT_OFF + ((size_t)n * B + bglob) * H + j] = cstp * CFX;
    }
}

extern "C" void kernel_launch(void* const* d_in, const int* in_sizes, int n_in,
                              void* d_out, int out_size, void* d_ws, size_t ws_size,
                              hipStream_t stream) {
    const float* X     = (const float*)d_in[0];
    const float* W_ih  = (const float*)d_in[1];
    const float* W_hh  = (const float*)d_in[2];
    const float* b_ih  = (const float*)d_in[3];
    const float* b_hh  = (const float*)d_in[4];
    const float* W_out = (const float*)d_in[5];
    const float* b_out = (const float*)d_in[6];
    float* out = (float*)d_out;

    const int xelems = 32 * 512 * 32;  // B*T*N
    const bool usebf = ws_size >= (size_t)xelems * sizeof(short);

    if (usebf) {
        short* Xb = (short*)d_ws;
        xcvt_kernel<<<dim3(xelems / 1024), dim3(256), 0, stream>>>(X, Xb, xelems);
        clstm_kernel<true><<<dim3(256), dim3(512), 0, stream>>>(
            X, Xb, W_ih, W_hh, b_ih, b_hh, W_out, b_out, out);
    } else {
        clstm_kernel<false><<<dim3(256), dim3(512), 0, stream>>>(
            X, nullptr, W_ih, W_hh, b_ih, b_hh, W_out, b_out, out);
    }
}